// Round 3
// baseline (321.219 us; speedup 1.0000x reference)
//
#include <hip/hip_runtime.h>
#include <math.h>

typedef float  f32x4  __attribute__((ext_vector_type(4)));
typedef short  bf16x8 __attribute__((ext_vector_type(8)));
typedef unsigned short u16x8 __attribute__((ext_vector_type(8)));
typedef unsigned short u16x4 __attribute__((ext_vector_type(4)));

#define B_ROWS 2048
#define D_DIM  512
#define W_DIM  512
#define N_NODES 63
#define N_BINS  64
#define K_TOT   32768   // 64 * 512
#define NSPLIT  8       // split over l-groups: 8 l's per z-block

__device__ __forceinline__ unsigned short f2bf(float f) {
    union { float f; unsigned int u; } v; v.f = f;
    unsigned int u = v.u;
    return (unsigned short)((u + 0x7fffu + ((u >> 16) & 1u)) >> 16);
}

__device__ __forceinline__ float sigmoidf_(float z) {
    return 1.0f / (1.0f + expf(-z));
}

// async global->LDS, 16 bytes per lane. LDS dest must be wave-uniform base + lane*16.
__device__ __forceinline__ void load_lds16(const void* g, void* l) {
    __builtin_amdgcn_global_load_lds(
        (const __attribute__((address_space(1))) unsigned int*)g,
        (__attribute__((address_space(3))) unsigned int*)l,
        16, 0, 0);
}

// ---------------- kernel 1: dist [2048,64] + xb = bf16(x) ------------------
// one wave per row; x values loaded for the norm reduction are reused for the
// bf16 conversion (no second pass over x).
__global__ __launch_bounds__(256) void k_prep(
    const float* __restrict__ x, const float* __restrict__ ray,
    const float* __restrict__ w_i, const float* __restrict__ b_i,
    const float* __restrict__ a_i, const int* __restrict__ idx,
    float* __restrict__ dist, unsigned short* __restrict__ xb)
{
    const int wid  = threadIdx.x >> 6;
    const int lane = threadIdx.x & 63;
    const int row  = blockIdx.x * 4 + wid;
    const float* xr = x + (size_t)row * D_DIM;

    float dotv = 0.f, xx = 0.f, rr = 0.f;
#pragma unroll
    for (int j = 0; j < 2; ++j) {
        f32x4 xv = *(const f32x4*)(xr  + j * 256 + lane * 4);
        f32x4 rv = *(const f32x4*)(ray + j * 256 + lane * 4);
        dotv += xv.x * rv.x + xv.y * rv.y + xv.z * rv.z + xv.w * rv.w;
        xx   += xv.x * xv.x + xv.y * xv.y + xv.z * xv.z + xv.w * xv.w;
        rr   += rv.x * rv.x + rv.y * rv.y + rv.z * rv.z + rv.w * rv.w;
        u16x4 o;
        o[0] = f2bf(xv.x); o[1] = f2bf(xv.y); o[2] = f2bf(xv.z); o[3] = f2bf(xv.w);
        *(u16x4*)(xb + (size_t)row * D_DIM + j * 256 + lane * 4) = o;
    }
#pragma unroll
    for (int off = 1; off < 64; off <<= 1) {
        dotv += __shfl_xor(dotv, off, 64);
        xx   += __shfl_xor(xx,   off, 64);
        rr   += __shfl_xor(rr,   off, 64);
    }
    float xn = fmaxf(sqrtf(xx), 1e-8f);
    float rn = fmaxf(sqrtf(rr), 1e-8f);
    float cosv = dotv / (xn * rn);
    cosv = fminf(1.f, fmaxf(-1.f, cosv));
    float angle = acosf(cosv) * 0.31830988618379067f; // 1/pi

    float dec = 0.f;
    if (lane < N_NODES) {
        float sw = sigmoidf_(w_i[lane]);
        float sb = sigmoidf_(b_i[lane]);
        float nf = (0.5f + sw) * angle - sb;
        dec = sigmoidf_(nf * (1.0f + a_i[lane]));
    }

    float p = 1.f;
#pragma unroll
    for (int v = 0; v < 6; ++v) {
        int j = idx[lane * 6 + v];
        int node = (j < N_NODES) ? j : j - N_NODES;
        float d = __shfl(dec, node, 64);
        p *= (j < N_NODES) ? d : (1.0f - d);
    }
    dist[(size_t)row * N_BINS + lane] = p;
}

// ---------------- kernel 2: transpose T[64][512][512] f32 -> Tt[512][32768] bf16
__global__ __launch_bounds__(256) void k_transpose2(
    const float* __restrict__ T, unsigned short* __restrict__ Tt)
{
    __shared__ float tile[64][65];
    const int l  = blockIdx.z;
    const int i0 = blockIdx.x * 64, w0 = blockIdx.y * 64;
    const int t  = threadIdx.x;

    const int w4 = (t & 15) * 4;
    const int ir = t >> 4;     // 0..15
    const float* src = T + ((size_t)(l * 512 + i0)) * 512 + w0;
#pragma unroll
    for (int p = 0; p < 4; ++p) {
        int i = ir + p * 16;
        f32x4 v = *(const f32x4*)(src + (size_t)i * 512 + w4);
        tile[i][w4 + 0] = v.x; tile[i][w4 + 1] = v.y;
        tile[i][w4 + 2] = v.z; tile[i][w4 + 3] = v.w;
    }
    __syncthreads();
#pragma unroll
    for (int rep = 0; rep < 2; ++rep) {
        int id = t + rep * 256;    // 0..511
        int w  = id >> 3;          // 0..63
        int c  = id & 7;           // i-chunk
        u16x8 o;
#pragma unroll
        for (int j = 0; j < 8; ++j) o[j] = f2bf(tile[c * 8 + j][w]);
        *(u16x8*)(Tt + (size_t)(w0 + w) * K_TOT + l * 512 + i0 + c * 8) = o;
    }
}

// ---------------- kernel 3: GEMM with dist folded into the accumulator -----
// out[m][n] = sum_l dist[m][l] * ( sum_{k in seg l} xb[m][k] * Tt[n][l*512+k] )
// A = xb (2 MiB, L2-resident). Per l-segment: 8 BK=64 iters accumulate acc_l,
// then one scale-accumulate pass into out_acc (64 FMA per 256 MFMA per wave).
__global__ __launch_bounds__(256, 2) void k_gemm3(
    const unsigned short* __restrict__ xb, const unsigned short* __restrict__ Tt,
    const float* __restrict__ dist, float* __restrict__ part)
{
    __shared__ unsigned short As[128 * 64];
    __shared__ unsigned short Bs[128 * 64];
    __shared__ float Ds[128 * 8];    // dist[row][lo] for this block's 8 l's

    const int bm0 = blockIdx.x * 128;
    const int bn0 = blockIdx.y * 128;
    const int l0  = blockIdx.z * (N_BINS / NSPLIT);

    const int t    = threadIdx.x;
    const int lane = t & 63;
    const int wid  = t >> 6;
    const int wm = wid >> 1, wn = wid & 1;
    const int lq = lane >> 4, lr = lane & 15;

    const int srow = t >> 3;   // 0..31 (+ j*32)
    const int c    = t & 7;    // LDS chunk slot

    // preload dist tile [128 rows][8 l's] -> LDS (coalesced f32x4)
    {
        int row = t >> 1, lo4 = (t & 1) * 4;
        f32x4 dv = *(const f32x4*)(dist + (size_t)(bm0 + row) * N_BINS + l0 + lo4);
        *(f32x4*)&Ds[row * 8 + lo4] = dv;
    }

    f32x4 out_acc[4][4];
#pragma unroll
    for (int a = 0; a < 4; ++a)
#pragma unroll
        for (int b = 0; b < 4; ++b)
            out_acc[a][b] = (f32x4){0.f, 0.f, 0.f, 0.f};

    for (int lo = 0; lo < N_BINS / NSPLIT; ++lo) {
        const int l = l0 + lo;
        f32x4 accl[4][4];
#pragma unroll
        for (int a = 0; a < 4; ++a)
#pragma unroll
            for (int b = 0; b < 4; ++b)
                accl[a][b] = (f32x4){0.f, 0.f, 0.f, 0.f};

        for (int it = 0; it < 8; ++it) {
            const int i0 = it * 64;
#pragma unroll
            for (int j = 0; j < 4; ++j) {
                int row = srow + j * 32;
                int cg  = c ^ (row & 7);
                load_lds16(xb + (size_t)(bm0 + row) * D_DIM + i0 + cg * 8,
                           &As[row * 64 + c * 8]);
                load_lds16(Tt + (size_t)(bn0 + row) * K_TOT + l * 512 + i0 + cg * 8,
                           &Bs[row * 64 + c * 8]);
            }
            __syncthreads();
#pragma unroll
            for (int ks = 0; ks < 2; ++ks) {
                bf16x8 af[4], bfr[4];
#pragma unroll
                for (int fm = 0; fm < 4; ++fm) {
                    int m = wm * 64 + fm * 16 + lr;
                    int g = ks * 4 + lq;
                    af[fm] = *(const bf16x8*)&As[m * 64 + ((g ^ (m & 7)) * 8)];
                }
#pragma unroll
                for (int fn = 0; fn < 4; ++fn) {
                    int n = wn * 64 + fn * 16 + lr;
                    int g = ks * 4 + lq;
                    bfr[fn] = *(const bf16x8*)&Bs[n * 64 + ((g ^ (n & 7)) * 8)];
                }
#pragma unroll
                for (int fm = 0; fm < 4; ++fm)
#pragma unroll
                    for (int fn = 0; fn < 4; ++fn)
                        accl[fm][fn] = __builtin_amdgcn_mfma_f32_16x16x32_bf16(
                            af[fm], bfr[fn], accl[fm][fn], 0, 0, 0);
            }
            __syncthreads();
        }
        // scale-accumulate: out_acc += dist[m,l] * accl  (per-row scalar)
#pragma unroll
        for (int fm = 0; fm < 4; ++fm) {
            float d[4];
#pragma unroll
            for (int r = 0; r < 4; ++r)
                d[r] = Ds[(wm * 64 + fm * 16 + lq * 4 + r) * 8 + lo];
#pragma unroll
            for (int fn = 0; fn < 4; ++fn)
#pragma unroll
                for (int r = 0; r < 4; ++r)
                    out_acc[fm][fn][r] += d[r] * accl[fm][fn][r];
        }
    }

    float* Cp = part + (size_t)blockIdx.z * (B_ROWS * W_DIM);
#pragma unroll
    for (int fm = 0; fm < 4; ++fm)
#pragma unroll
        for (int fn = 0; fn < 4; ++fn)
#pragma unroll
            for (int r = 0; r < 4; ++r) {
                int row = bm0 + wm * 64 + fm * 16 + lq * 4 + r;
                int col = bn0 + wn * 64 + fn * 16 + lr;
                Cp[(size_t)row * W_DIM + col] = out_acc[fm][fn][r];
            }
}

// ---------------- kernel 4: split-K reduction ------------------------------
__global__ __launch_bounds__(256) void k_reduce(
    const float* __restrict__ part, float* __restrict__ out, int nsplit)
{
    int i = (blockIdx.x * 256 + threadIdx.x) * 4;
    f32x4 s = *(const f32x4*)(part + i);
    for (int p = 1; p < nsplit; ++p)
        s += *(const f32x4*)(part + (size_t)p * (B_ROWS * W_DIM) + i);
    *(f32x4*)(out + i) = s;
}

// ---------------- fallback GEMM (round-1 path, VGPR staging) ---------------
__global__ __launch_bounds__(256, 2) void k_gemm_bt(
    const float* __restrict__ x, const float* __restrict__ dist,
    const unsigned short* __restrict__ Tt, float* __restrict__ part,
    int kchunk)
{
    __shared__ unsigned short As[128][72];
    __shared__ unsigned short Bs[128][64];

    const int bm0 = blockIdx.x * 128;
    const int bn0 = blockIdx.y * 128;
    const int kbase = blockIdx.z * kchunk;

    const int lane = threadIdx.x & 63;
    const int wid  = threadIdx.x >> 6;
    const int wm = wid >> 1, wn = wid & 1;
    const int lq = lane >> 4, lr = lane & 15;

    f32x4 acc[4][4];
#pragma unroll
    for (int a = 0; a < 4; ++a)
#pragma unroll
        for (int b = 0; b < 4; ++b)
            acc[a][b] = (f32x4){0.f, 0.f, 0.f, 0.f};

    const int iters = kchunk / 64;
    for (int it = 0; it < iters; ++it) {
        const int k0 = kbase + it * 64;
        const int l  = k0 >> 9;
        const int i0 = k0 & 511;
#pragma unroll
        for (int r2 = 0; r2 < 8; ++r2) {
            int id = threadIdx.x + r2 * 256;
            int m  = id >> 4;
            int kc = id & 15;
            float sc = dist[(size_t)(bm0 + m) * N_BINS + l];
            f32x4 v = *(const f32x4*)(x + (size_t)(bm0 + m) * D_DIM + i0 + kc * 4);
            v *= sc;
            unsigned int p0 = (unsigned int)f2bf(v.x) | ((unsigned int)f2bf(v.y) << 16);
            unsigned int p1 = (unsigned int)f2bf(v.z) | ((unsigned int)f2bf(v.w) << 16);
            unsigned int* dp = (unsigned int*)&As[m][kc * 4];
            dp[0] = p0; dp[1] = p1;
        }
#pragma unroll
        for (int r2 = 0; r2 < 4; ++r2) {
            int id = threadIdx.x + r2 * 256;
            int n  = id >> 3;
            int cc = id & 7;
            int cg = cc ^ (n & 7);
            const u16x8 v = *(const u16x8*)(Tt + (size_t)(bn0 + n) * K_TOT + k0 + cg * 8);
            *(u16x8*)&Bs[n][cc * 8] = v;
        }
        __syncthreads();
#pragma unroll
        for (int ks = 0; ks < 2; ++ks) {
            bf16x8 af[4], bfr[4];
#pragma unroll
            for (int fm = 0; fm < 4; ++fm)
                af[fm] = *(const bf16x8*)&As[wm * 64 + fm * 16 + lr][ks * 32 + lq * 8];
#pragma unroll
            for (int fn = 0; fn < 4; ++fn) {
                int nl = wn * 64 + fn * 16 + lr;
                int cs = (ks * 4 + lq) ^ (nl & 7);
                bfr[fn] = *(const bf16x8*)&Bs[nl][cs * 8];
            }
#pragma unroll
            for (int fm = 0; fm < 4; ++fm)
#pragma unroll
                for (int fn = 0; fn < 4; ++fn)
                    acc[fm][fn] = __builtin_amdgcn_mfma_f32_16x16x32_bf16(
                        af[fm], bfr[fn], acc[fm][fn], 0, 0, 0);
        }
        __syncthreads();
    }

    float* Cp = part + (size_t)blockIdx.z * (B_ROWS * W_DIM);
#pragma unroll
    for (int fm = 0; fm < 4; ++fm)
#pragma unroll
        for (int fn = 0; fn < 4; ++fn)
#pragma unroll
            for (int r = 0; r < 4; ++r) {
                int row = bm0 + wm * 64 + fm * 16 + lq * 4 + r;
                int col = bn0 + wn * 64 + fn * 16 + lr;
                Cp[(size_t)row * W_DIM + col] = acc[fm][fn][r];
            }
}

extern "C" void kernel_launch(void* const* d_in, const int* in_sizes, int n_in,
                              void* d_out, int out_size, void* d_ws, size_t ws_size,
                              hipStream_t stream) {
    const float* x   = (const float*)d_in[0];
    const float* ray = (const float*)d_in[1];
    const float* w_i = (const float*)d_in[2];
    const float* b_i = (const float*)d_in[3];
    const float* a_i = (const float*)d_in[4];
    const float* T   = (const float*)d_in[5];
    const int*   idx = (const int*)d_in[6];
    float* out = (float*)d_out;

    char* ws = (char*)d_ws;
    const size_t distBytes = (size_t)B_ROWS * N_BINS * 4;        // 512 KiB
    const size_t xbBytes   = (size_t)B_ROWS * D_DIM * 2;         // 2 MiB
    const size_t ttBytes   = (size_t)W_DIM * K_TOT * 2;          // 32 MiB
    const size_t partBytes = (size_t)B_ROWS * W_DIM * 4;         // 4 MiB per split

    if (ws_size >= distBytes + xbBytes + ttBytes + (size_t)NSPLIT * partBytes) {
        // -------- path A: dist-in-accumulator GEMM --------
        float*          dist = (float*)ws;
        unsigned short* xb   = (unsigned short*)(ws + distBytes);
        unsigned short* Tt   = (unsigned short*)(ws + distBytes + xbBytes);
        float*          part = (float*)(ws + distBytes + xbBytes + ttBytes);

        k_prep<<<B_ROWS / 4, 256, 0, stream>>>(x, ray, w_i, b_i, a_i, idx, dist, xb);
        k_transpose2<<<dim3(8, 8, 64), 256, 0, stream>>>(T, Tt);
        k_gemm3<<<dim3(16, 4, NSPLIT), 256, 0, stream>>>(xb, Tt, dist, part);
        k_reduce<<<(B_ROWS * W_DIM) / (256 * 4), 256, 0, stream>>>(part, out, NSPLIT);
    } else if (ws_size >= distBytes + xbBytes + ttBytes) {
        // -------- path B: round-1 structure, nsplit=1 direct to out --------
        float*          dist = (float*)ws;
        unsigned short* xb   = (unsigned short*)(ws + distBytes);
        unsigned short* Tt   = (unsigned short*)(ws + distBytes + xbBytes);
        k_prep<<<B_ROWS / 4, 256, 0, stream>>>(x, ray, w_i, b_i, a_i, idx, dist, xb);
        k_transpose2<<<dim3(8, 8, 64), 256, 0, stream>>>(T, Tt);
        k_gemm_bt<<<dim3(16, 4, 1), 256, 0, stream>>>(x, dist, Tt, out, K_TOT);
    }
}

// Round 4
// 286.435 us; speedup vs baseline: 1.1214x; 1.1214x over previous
//
#include <hip/hip_runtime.h>
#include <math.h>

typedef float  f32x4  __attribute__((ext_vector_type(4)));
typedef short  bf16x8 __attribute__((ext_vector_type(8)));
typedef unsigned short u16x8 __attribute__((ext_vector_type(8)));
typedef unsigned short u16x4 __attribute__((ext_vector_type(4)));

#define B_ROWS 2048
#define D_DIM  512
#define W_DIM  512
#define N_NODES 63
#define N_BINS  64
#define K_TOT   32768   // 64 * 512
#define NSPLIT  8       // split over l-groups: 8 l's per z-slot

__device__ __forceinline__ unsigned short f2bf(float f) {
    union { float f; unsigned int u; } v; v.f = f;
    unsigned int u = v.u;
    return (unsigned short)((u + 0x7fffu + ((u >> 16) & 1u)) >> 16);
}

__device__ __forceinline__ float sigmoidf_(float z) {
    return 1.0f / (1.0f + expf(-z));
}

// async global->LDS, 16 bytes per lane. LDS dest must be wave-uniform base + lane*16.
__device__ __forceinline__ void load_lds16(const void* g, void* l) {
    __builtin_amdgcn_global_load_lds(
        (const __attribute__((address_space(1))) unsigned int*)g,
        (__attribute__((address_space(3))) unsigned int*)l,
        16, 0, 0);
}

// ---------------- kernel 1: dist [2048,64] + xb = bf16(x) ------------------
__global__ __launch_bounds__(256) void k_prep(
    const float* __restrict__ x, const float* __restrict__ ray,
    const float* __restrict__ w_i, const float* __restrict__ b_i,
    const float* __restrict__ a_i, const int* __restrict__ idx,
    float* __restrict__ dist, unsigned short* __restrict__ xb)
{
    const int wid  = threadIdx.x >> 6;
    const int lane = threadIdx.x & 63;
    const int row  = blockIdx.x * 4 + wid;
    const float* xr = x + (size_t)row * D_DIM;

    float dotv = 0.f, xx = 0.f, rr = 0.f;
#pragma unroll
    for (int j = 0; j < 2; ++j) {
        f32x4 xv = *(const f32x4*)(xr  + j * 256 + lane * 4);
        f32x4 rv = *(const f32x4*)(ray + j * 256 + lane * 4);
        dotv += xv.x * rv.x + xv.y * rv.y + xv.z * rv.z + xv.w * rv.w;
        xx   += xv.x * xv.x + xv.y * xv.y + xv.z * xv.z + xv.w * xv.w;
        rr   += rv.x * rv.x + rv.y * rv.y + rv.z * rv.z + rv.w * rv.w;
        u16x4 o;
        o[0] = f2bf(xv.x); o[1] = f2bf(xv.y); o[2] = f2bf(xv.z); o[3] = f2bf(xv.w);
        *(u16x4*)(xb + (size_t)row * D_DIM + j * 256 + lane * 4) = o;
    }
#pragma unroll
    for (int off = 1; off < 64; off <<= 1) {
        dotv += __shfl_xor(dotv, off, 64);
        xx   += __shfl_xor(xx,   off, 64);
        rr   += __shfl_xor(rr,   off, 64);
    }
    float xn = fmaxf(sqrtf(xx), 1e-8f);
    float rn = fmaxf(sqrtf(rr), 1e-8f);
    float cosv = dotv / (xn * rn);
    cosv = fminf(1.f, fmaxf(-1.f, cosv));
    float angle = acosf(cosv) * 0.31830988618379067f; // 1/pi

    float dec = 0.f;
    if (lane < N_NODES) {
        float sw = sigmoidf_(w_i[lane]);
        float sb = sigmoidf_(b_i[lane]);
        float nf = (0.5f + sw) * angle - sb;
        dec = sigmoidf_(nf * (1.0f + a_i[lane]));
    }

    float p = 1.f;
#pragma unroll
    for (int v = 0; v < 6; ++v) {
        int j = idx[lane * 6 + v];
        int node = (j < N_NODES) ? j : j - N_NODES;
        float d = __shfl(dec, node, 64);
        p *= (j < N_NODES) ? d : (1.0f - d);
    }
    dist[(size_t)row * N_BINS + lane] = p;
}

// ---------------- kernel 2: transpose T[64][512][512] f32 -> Tt[512][32768] bf16
__global__ __launch_bounds__(256) void k_transpose2(
    const float* __restrict__ T, unsigned short* __restrict__ Tt)
{
    __shared__ float tile[64][65];
    const int l  = blockIdx.z;
    const int i0 = blockIdx.x * 64, w0 = blockIdx.y * 64;
    const int t  = threadIdx.x;

    const int w4 = (t & 15) * 4;
    const int ir = t >> 4;     // 0..15
    const float* src = T + ((size_t)(l * 512 + i0)) * 512 + w0;
#pragma unroll
    for (int p = 0; p < 4; ++p) {
        int i = ir + p * 16;
        f32x4 v = *(const f32x4*)(src + (size_t)i * 512 + w4);
        tile[i][w4 + 0] = v.x; tile[i][w4 + 1] = v.y;
        tile[i][w4 + 2] = v.z; tile[i][w4 + 3] = v.w;
    }
    __syncthreads();
#pragma unroll
    for (int rep = 0; rep < 2; ++rep) {
        int id = t + rep * 256;    // 0..511
        int w  = id >> 3;          // 0..63
        int c  = id & 7;           // i-chunk
        u16x8 o;
#pragma unroll
        for (int j = 0; j < 8; ++j) o[j] = f2bf(tile[c * 8 + j][w]);
        *(u16x8*)(Tt + (size_t)(w0 + w) * K_TOT + l * 512 + i0 + c * 8) = o;
    }
}

// ---------------- kernel 3: dist-in-accumulator GEMM, spill-free -----------
// 512 threads, 8 waves as 2(m)x4(n), 64x32 wave tile -> 32+32 acc floats.
// Linear grid of 512 blocks, XCD-combo swizzle: XCD x gets combos
// [4x, 4x+4) x all 16 m-blocks consecutively -> B-slice (1MB) + xb (2MB)
// stay in that XCD's 4MB L2.
__global__ __launch_bounds__(512, 2) void k_gemm4(
    const unsigned short* __restrict__ xb, const unsigned short* __restrict__ Tt,
    const float* __restrict__ dist, float* __restrict__ part)
{
    __shared__ unsigned short As[128 * 64];
    __shared__ unsigned short Bs[128 * 64];
    __shared__ float Ds[128 * 8];

    const int b   = blockIdx.x;
    const int xcd = b & 7;
    const int j   = b >> 3;               // 0..63
    const int combo = xcd * 4 + (j >> 4); // 0..31
    const int mblk  = j & 15;
    const int bm0 = mblk * 128;
    const int bn0 = (combo & 3) * 128;
    const int z   = combo >> 2;           // 0..7
    const int l0  = z * (N_BINS / NSPLIT);

    const int t    = threadIdx.x;
    const int lane = t & 63;
    const int wid  = t >> 6;              // 0..7
    const int wm = wid >> 2, wn = wid & 3;
    const int lq = lane >> 4, lr = lane & 15;

    // preload dist tile [128 rows][8 l's] -> LDS
    if (t < 256) {
        int row = t >> 1, lo4 = (t & 1) * 4;
        f32x4 dv = *(const f32x4*)(dist + (size_t)(bm0 + row) * N_BINS + l0 + lo4);
        *(f32x4*)&Ds[row * 8 + lo4] = dv;
    }

    f32x4 out_acc[4][2];
#pragma unroll
    for (int a = 0; a < 4; ++a)
#pragma unroll
        for (int bb = 0; bb < 2; ++bb)
            out_acc[a][bb] = (f32x4){0.f, 0.f, 0.f, 0.f};

    for (int lo = 0; lo < N_BINS / NSPLIT; ++lo) {
        const int l = l0 + lo;
        f32x4 accl[4][2];
#pragma unroll
        for (int a = 0; a < 4; ++a)
#pragma unroll
            for (int bb = 0; bb < 2; ++bb)
                accl[a][bb] = (f32x4){0.f, 0.f, 0.f, 0.f};

        for (int it = 0; it < 8; ++it) {
            const int i0 = it * 64;
#pragma unroll
            for (int jj = 0; jj < 2; ++jj) {
                int chunk = t + jj * 512;        // 0..1023
                int row = chunk >> 3;
                int c   = chunk & 7;
                int cg  = c ^ (row & 7);
                load_lds16(xb + (size_t)(bm0 + row) * D_DIM + i0 + cg * 8,
                           &As[chunk * 8]);
                load_lds16(Tt + (size_t)(bn0 + row) * K_TOT + l * 512 + i0 + cg * 8,
                           &Bs[chunk * 8]);
            }
            __syncthreads();
#pragma unroll
            for (int ks = 0; ks < 2; ++ks) {
                bf16x8 af[4], bfr[2];
#pragma unroll
                for (int fm = 0; fm < 4; ++fm) {
                    int m = wm * 64 + fm * 16 + lr;
                    int g = ks * 4 + lq;
                    af[fm] = *(const bf16x8*)&As[m * 64 + ((g ^ (m & 7)) * 8)];
                }
#pragma unroll
                for (int fn = 0; fn < 2; ++fn) {
                    int n = wn * 32 + fn * 16 + lr;
                    int g = ks * 4 + lq;
                    bfr[fn] = *(const bf16x8*)&Bs[n * 64 + ((g ^ (n & 7)) * 8)];
                }
#pragma unroll
                for (int fm = 0; fm < 4; ++fm)
#pragma unroll
                    for (int fn = 0; fn < 2; ++fn)
                        accl[fm][fn] = __builtin_amdgcn_mfma_f32_16x16x32_bf16(
                            af[fm], bfr[fn], accl[fm][fn], 0, 0, 0);
            }
            __syncthreads();
        }
        // out_acc += dist[m,l] * accl   (per-row scalar, broadcast LDS read)
#pragma unroll
        for (int fm = 0; fm < 4; ++fm) {
            float d[4];
#pragma unroll
            for (int r = 0; r < 4; ++r)
                d[r] = Ds[(wm * 64 + fm * 16 + lq * 4 + r) * 8 + lo];
#pragma unroll
            for (int fn = 0; fn < 2; ++fn)
#pragma unroll
                for (int r = 0; r < 4; ++r)
                    out_acc[fm][fn][r] += d[r] * accl[fm][fn][r];
        }
    }

    float* Cp = part + (size_t)z * (B_ROWS * W_DIM);
#pragma unroll
    for (int fm = 0; fm < 4; ++fm)
#pragma unroll
        for (int fn = 0; fn < 2; ++fn)
#pragma unroll
            for (int r = 0; r < 4; ++r) {
                int row = bm0 + wm * 64 + fm * 16 + lq * 4 + r;
                int col = bn0 + wn * 32 + fn * 16 + lr;
                Cp[(size_t)row * W_DIM + col] = out_acc[fm][fn][r];
            }
}

// ---------------- kernel 4: split reduction --------------------------------
__global__ __launch_bounds__(256) void k_reduce(
    const float* __restrict__ part, float* __restrict__ out, int nsplit)
{
    int i = (blockIdx.x * 256 + threadIdx.x) * 4;
    f32x4 s = *(const f32x4*)(part + i);
    for (int p = 1; p < nsplit; ++p)
        s += *(const f32x4*)(part + (size_t)p * (B_ROWS * W_DIM) + i);
    *(f32x4*)(out + i) = s;
}

// ---------------- fallback GEMM (round-1 path, VGPR staging) ---------------
__global__ __launch_bounds__(256, 2) void k_gemm_bt(
    const float* __restrict__ x, const float* __restrict__ dist,
    const unsigned short* __restrict__ Tt, float* __restrict__ part,
    int kchunk)
{
    __shared__ unsigned short As[128][72];
    __shared__ unsigned short Bs[128][64];

    const int bm0 = blockIdx.x * 128;
    const int bn0 = blockIdx.y * 128;
    const int kbase = blockIdx.z * kchunk;

    const int lane = threadIdx.x & 63;
    const int wid  = threadIdx.x >> 6;
    const int wm = wid >> 1, wn = wid & 1;
    const int lq = lane >> 4, lr = lane & 15;

    f32x4 acc[4][4];
#pragma unroll
    for (int a = 0; a < 4; ++a)
#pragma unroll
        for (int b = 0; b < 4; ++b)
            acc[a][b] = (f32x4){0.f, 0.f, 0.f, 0.f};

    const int iters = kchunk / 64;
    for (int it = 0; it < iters; ++it) {
        const int k0 = kbase + it * 64;
        const int l  = k0 >> 9;
        const int i0 = k0 & 511;
#pragma unroll
        for (int r2 = 0; r2 < 8; ++r2) {
            int id = threadIdx.x + r2 * 256;
            int m  = id >> 4;
            int kc = id & 15;
            float sc = dist[(size_t)(bm0 + m) * N_BINS + l];
            f32x4 v = *(const f32x4*)(x + (size_t)(bm0 + m) * D_DIM + i0 + kc * 4);
            v *= sc;
            unsigned int p0 = (unsigned int)f2bf(v.x) | ((unsigned int)f2bf(v.y) << 16);
            unsigned int p1 = (unsigned int)f2bf(v.z) | ((unsigned int)f2bf(v.w) << 16);
            unsigned int* dp = (unsigned int*)&As[m][kc * 4];
            dp[0] = p0; dp[1] = p1;
        }
#pragma unroll
        for (int r2 = 0; r2 < 4; ++r2) {
            int id = threadIdx.x + r2 * 256;
            int n  = id >> 3;
            int cc = id & 7;
            int cg = cc ^ (n & 7);
            const u16x8 v = *(const u16x8*)(Tt + (size_t)(bn0 + n) * K_TOT + k0 + cg * 8);
            *(u16x8*)&Bs[n][cc * 8] = v;
        }
        __syncthreads();
#pragma unroll
        for (int ks = 0; ks < 2; ++ks) {
            bf16x8 af[4], bfr[4];
#pragma unroll
            for (int fm = 0; fm < 4; ++fm)
                af[fm] = *(const bf16x8*)&As[wm * 64 + fm * 16 + lr][ks * 32 + lq * 8];
#pragma unroll
            for (int fn = 0; fn < 4; ++fn) {
                int nl = wn * 64 + fn * 16 + lr;
                int cs = (ks * 4 + lq) ^ (nl & 7);
                bfr[fn] = *(const bf16x8*)&Bs[nl][cs * 8];
            }
#pragma unroll
            for (int fm = 0; fm < 4; ++fm)
#pragma unroll
                for (int fn = 0; fn < 4; ++fn)
                    acc[fm][fn] = __builtin_amdgcn_mfma_f32_16x16x32_bf16(
                        af[fm], bfr[fn], acc[fm][fn], 0, 0, 0);
        }
        __syncthreads();
    }

    float* Cp = part + (size_t)blockIdx.z * (B_ROWS * W_DIM);
#pragma unroll
    for (int fm = 0; fm < 4; ++fm)
#pragma unroll
        for (int fn = 0; fn < 4; ++fn)
#pragma unroll
            for (int r = 0; r < 4; ++r) {
                int row = bm0 + wm * 64 + fm * 16 + lq * 4 + r;
                int col = bn0 + wn * 64 + fn * 16 + lr;
                Cp[(size_t)row * W_DIM + col] = acc[fm][fn][r];
            }
}

extern "C" void kernel_launch(void* const* d_in, const int* in_sizes, int n_in,
                              void* d_out, int out_size, void* d_ws, size_t ws_size,
                              hipStream_t stream) {
    const float* x   = (const float*)d_in[0];
    const float* ray = (const float*)d_in[1];
    const float* w_i = (const float*)d_in[2];
    const float* b_i = (const float*)d_in[3];
    const float* a_i = (const float*)d_in[4];
    const float* T   = (const float*)d_in[5];
    const int*   idx = (const int*)d_in[6];
    float* out = (float*)d_out;

    char* ws = (char*)d_ws;
    const size_t distBytes = (size_t)B_ROWS * N_BINS * 4;        // 512 KiB
    const size_t xbBytes   = (size_t)B_ROWS * D_DIM * 2;         // 2 MiB
    const size_t ttBytes   = (size_t)W_DIM * K_TOT * 2;          // 32 MiB
    const size_t partBytes = (size_t)B_ROWS * W_DIM * 4;         // 4 MiB per split

    if (ws_size >= distBytes + xbBytes + ttBytes + (size_t)NSPLIT * partBytes) {
        // -------- path A: dist-in-accumulator GEMM, XCD-swizzled --------
        float*          dist = (float*)ws;
        unsigned short* xb   = (unsigned short*)(ws + distBytes);
        unsigned short* Tt   = (unsigned short*)(ws + distBytes + xbBytes);
        float*          part = (float*)(ws + distBytes + xbBytes + ttBytes);

        k_prep<<<B_ROWS / 4, 256, 0, stream>>>(x, ray, w_i, b_i, a_i, idx, dist, xb);
        k_transpose2<<<dim3(8, 8, 64), 256, 0, stream>>>(T, Tt);
        k_gemm4<<<512, 512, 0, stream>>>(xb, Tt, dist, part);
        k_reduce<<<(B_ROWS * W_DIM) / (256 * 4), 256, 0, stream>>>(part, out, NSPLIT);
    } else if (ws_size >= distBytes + xbBytes + ttBytes) {
        // -------- path B: round-1 structure, nsplit=1 direct to out --------
        float*          dist = (float*)ws;
        unsigned short* xb   = (unsigned short*)(ws + distBytes);
        unsigned short* Tt   = (unsigned short*)(ws + distBytes + xbBytes);
        k_prep<<<B_ROWS / 4, 256, 0, stream>>>(x, ray, w_i, b_i, a_i, idx, dist, xb);
        k_transpose2<<<dim3(8, 8, 64), 256, 0, stream>>>(T, Tt);
        k_gemm_bt<<<dim3(16, 4, 1), 256, 0, stream>>>(x, dist, Tt, out, K_TOT);
    }
}

// Round 5
// 248.872 us; speedup vs baseline: 1.2907x; 1.1509x over previous
//
#include <hip/hip_runtime.h>
#include <math.h>

typedef float  f32x4  __attribute__((ext_vector_type(4)));
typedef short  bf16x8 __attribute__((ext_vector_type(8)));
typedef unsigned short u16x8 __attribute__((ext_vector_type(8)));
typedef unsigned short u16x4 __attribute__((ext_vector_type(4)));

#define B_ROWS 2048
#define D_DIM  512
#define W_DIM  512
#define N_NODES 63
#define N_BINS  64
#define K_TOT   32768   // 64 * 512
#define NSPLIT  8       // 8 l's per z-slot
#define DEPS    1e-12f

__device__ __forceinline__ unsigned short f2bf(float f) {
    union { float f; unsigned int u; } v; v.f = f;
    unsigned int u = v.u;
    return (unsigned short)((u + 0x7fffu + ((u >> 16) & 1u)) >> 16);
}

__device__ __forceinline__ float sigmoidf_(float z) {
    return 1.0f / (1.0f + expf(-z));
}

// async global->LDS, 16 bytes per lane. LDS dest must be wave-uniform base + lane*16.
__device__ __forceinline__ void load_lds16(const void* g, void* l) {
    __builtin_amdgcn_global_load_lds(
        (const __attribute__((address_space(1))) unsigned int*)g,
        (__attribute__((address_space(3))) unsigned int*)l,
        16, 0, 0);
}

// ---------------- kernel 1: dist [2048,64] + xb = bf16(x) ------------------
__global__ __launch_bounds__(256) void k_prep(
    const float* __restrict__ x, const float* __restrict__ ray,
    const float* __restrict__ w_i, const float* __restrict__ b_i,
    const float* __restrict__ a_i, const int* __restrict__ idx,
    float* __restrict__ dist, unsigned short* __restrict__ xb)
{
    const int wid  = threadIdx.x >> 6;
    const int lane = threadIdx.x & 63;
    const int row  = blockIdx.x * 4 + wid;
    const float* xr = x + (size_t)row * D_DIM;

    float dotv = 0.f, xx = 0.f, rr = 0.f;
#pragma unroll
    for (int j = 0; j < 2; ++j) {
        f32x4 xv = *(const f32x4*)(xr  + j * 256 + lane * 4);
        f32x4 rv = *(const f32x4*)(ray + j * 256 + lane * 4);
        dotv += xv.x * rv.x + xv.y * rv.y + xv.z * rv.z + xv.w * rv.w;
        xx   += xv.x * xv.x + xv.y * xv.y + xv.z * xv.z + xv.w * xv.w;
        rr   += rv.x * rv.x + rv.y * rv.y + rv.z * rv.z + rv.w * rv.w;
        u16x4 o;
        o[0] = f2bf(xv.x); o[1] = f2bf(xv.y); o[2] = f2bf(xv.z); o[3] = f2bf(xv.w);
        *(u16x4*)(xb + (size_t)row * D_DIM + j * 256 + lane * 4) = o;
    }
#pragma unroll
    for (int off = 1; off < 64; off <<= 1) {
        dotv += __shfl_xor(dotv, off, 64);
        xx   += __shfl_xor(xx,   off, 64);
        rr   += __shfl_xor(rr,   off, 64);
    }
    float xn = fmaxf(sqrtf(xx), 1e-8f);
    float rn = fmaxf(sqrtf(rr), 1e-8f);
    float cosv = dotv / (xn * rn);
    cosv = fminf(1.f, fmaxf(-1.f, cosv));
    float angle = acosf(cosv) * 0.31830988618379067f; // 1/pi

    float dec = 0.f;
    if (lane < N_NODES) {
        float sw = sigmoidf_(w_i[lane]);
        float sb = sigmoidf_(b_i[lane]);
        float nf = (0.5f + sw) * angle - sb;
        dec = sigmoidf_(nf * (1.0f + a_i[lane]));
    }

    float p = 1.f;
#pragma unroll
    for (int v = 0; v < 6; ++v) {
        int j = idx[lane * 6 + v];
        int node = (j < N_NODES) ? j : j - N_NODES;
        float d = __shfl(dec, node, 64);
        p *= (j < N_NODES) ? d : (1.0f - d);
    }
    dist[(size_t)row * N_BINS + lane] = p;
}

// ---------------- kernel 2: transpose T[64][512][512] f32 -> Tt[512][32768] bf16
__global__ __launch_bounds__(256) void k_transpose2(
    const float* __restrict__ T, unsigned short* __restrict__ Tt)
{
    __shared__ float tile[64][65];
    const int l  = blockIdx.z;
    const int i0 = blockIdx.x * 64, w0 = blockIdx.y * 64;
    const int t  = threadIdx.x;

    const int w4 = (t & 15) * 4;
    const int ir = t >> 4;     // 0..15
    const float* src = T + ((size_t)(l * 512 + i0)) * 512 + w0;
#pragma unroll
    for (int p = 0; p < 4; ++p) {
        int i = ir + p * 16;
        f32x4 v = *(const f32x4*)(src + (size_t)i * 512 + w4);
        tile[i][w4 + 0] = v.x; tile[i][w4 + 1] = v.y;
        tile[i][w4 + 2] = v.z; tile[i][w4 + 3] = v.w;
    }
    __syncthreads();
#pragma unroll
    for (int rep = 0; rep < 2; ++rep) {
        int id = t + rep * 256;    // 0..511
        int w  = id >> 3;          // 0..63
        int c  = id & 7;           // i-chunk
        u16x8 o;
#pragma unroll
        for (int j = 0; j < 8; ++j) o[j] = f2bf(tile[c * 8 + j][w]);
        *(u16x8*)(Tt + (size_t)(w0 + w) * K_TOT + l * 512 + i0 + c * 8) = o;
    }
}

// ---------------- kernel 3: online-rescaled dist-fold GEMM -----------------
// Single accumulator (k_gemm2 register shape). acc is kept in units of the
// current segment's dist value dc[l] (clamped): at each segment boundary
// acc *= dc[l-1]/dc[l]; epilogue multiplies by dc[7]. Telescoping gives each
// segment weight exactly dc[l].
__global__ __launch_bounds__(256, 4) void k_gemm5(
    const unsigned short* __restrict__ xb, const unsigned short* __restrict__ Tt,
    const float* __restrict__ dist, float* __restrict__ part)
{
    __shared__ unsigned short As[128 * 64];
    __shared__ unsigned short Bs[128 * 64];
    __shared__ float Ds[128 * 8];

    // XCD-combo swizzle: round-robin blockIdx->XCD; XCD x owns combos
    // [4x,4x+4) over all 16 m-blocks.
    const int b   = blockIdx.x;
    const int xcd = b & 7;
    const int j   = b >> 3;               // 0..63
    const int combo = xcd * 4 + (j >> 4); // 0..31
    const int mblk  = j & 15;
    const int bm0 = mblk * 128;
    const int bn0 = (combo & 3) * 128;
    const int z   = combo >> 2;           // 0..7
    const int l0  = z * (N_BINS / NSPLIT);

    const int t    = threadIdx.x;
    const int lane = t & 63;
    const int wid  = t >> 6;
    const int wm = wid >> 1, wn = wid & 1;
    const int lq = lane >> 4, lr = lane & 15;

    const int srow = t >> 3;   // 0..31 (+ j*32)
    const int c    = t & 7;    // LDS chunk slot

    // preload dist tile [128 rows][8 l's] -> LDS
    {
        int row = t >> 1, lo4 = (t & 1) * 4;
        f32x4 dv = *(const f32x4*)(dist + (size_t)(bm0 + row) * N_BINS + l0 + lo4);
        *(f32x4*)&Ds[row * 8 + lo4] = dv;
    }
    __syncthreads();

    f32x4 acc[4][4];
#pragma unroll
    for (int a = 0; a < 4; ++a)
#pragma unroll
        for (int bb = 0; bb < 4; ++bb)
            acc[a][bb] = (f32x4){0.f, 0.f, 0.f, 0.f};

    for (int lo = 0; lo < N_BINS / NSPLIT; ++lo) {
        const int l = l0 + lo;

        // segment-boundary rescale: acc *= dc[lo-1]/dc[lo]
        if (lo > 0) {
#pragma unroll
            for (int fm = 0; fm < 4; ++fm)
#pragma unroll
                for (int r = 0; r < 4; ++r) {
                    int m = wm * 64 + fm * 16 + lq * 4 + r;
                    float dp = fmaxf(Ds[m * 8 + lo - 1], DEPS);
                    float dn = fmaxf(Ds[m * 8 + lo],     DEPS);
                    float ratio = dp * __builtin_amdgcn_rcpf(dn);
#pragma unroll
                    for (int fn = 0; fn < 4; ++fn)
                        acc[fm][fn][r] *= ratio;
                }
        }

        for (int it = 0; it < 8; ++it) {
            const int i0 = it * 64;
#pragma unroll
            for (int jj = 0; jj < 4; ++jj) {
                int row = srow + jj * 32;
                int cg  = c ^ (row & 7);
                load_lds16(xb + (size_t)(bm0 + row) * D_DIM + i0 + cg * 8,
                           &As[row * 64 + c * 8]);
                load_lds16(Tt + (size_t)(bn0 + row) * K_TOT + l * 512 + i0 + cg * 8,
                           &Bs[row * 64 + c * 8]);
            }
            __syncthreads();
#pragma unroll
            for (int ks = 0; ks < 2; ++ks) {
                bf16x8 af[4], bfr[4];
#pragma unroll
                for (int fm = 0; fm < 4; ++fm) {
                    int m = wm * 64 + fm * 16 + lr;
                    int g = ks * 4 + lq;
                    af[fm] = *(const bf16x8*)&As[m * 64 + ((g ^ (m & 7)) * 8)];
                }
#pragma unroll
                for (int fn = 0; fn < 4; ++fn) {
                    int n = wn * 64 + fn * 16 + lr;
                    int g = ks * 4 + lq;
                    bfr[fn] = *(const bf16x8*)&Bs[n * 64 + ((g ^ (n & 7)) * 8)];
                }
#pragma unroll
                for (int fm = 0; fm < 4; ++fm)
#pragma unroll
                    for (int fn = 0; fn < 4; ++fn)
                        acc[fm][fn] = __builtin_amdgcn_mfma_f32_16x16x32_bf16(
                            af[fm], bfr[fn], acc[fm][fn], 0, 0, 0);
            }
            __syncthreads();
        }
    }

    // epilogue: multiply by dc[7] and store partial
    float* Cp = part + (size_t)z * (B_ROWS * W_DIM);
#pragma unroll
    for (int fm = 0; fm < 4; ++fm)
#pragma unroll
        for (int r = 0; r < 4; ++r) {
            int m = wm * 64 + fm * 16 + lq * 4 + r;
            float dl = fmaxf(Ds[m * 8 + 7], DEPS);
#pragma unroll
            for (int fn = 0; fn < 4; ++fn) {
                int col = bn0 + wn * 64 + fn * 16 + lr;
                Cp[(size_t)(bm0 + m) * W_DIM + col] = acc[fm][fn][r] * dl;
            }
        }
}

// ---------------- kernel 4: split reduction --------------------------------
__global__ __launch_bounds__(256) void k_reduce(
    const float* __restrict__ part, float* __restrict__ out, int nsplit)
{
    int i = (blockIdx.x * 256 + threadIdx.x) * 4;
    f32x4 s = *(const f32x4*)(part + i);
    for (int p = 1; p < nsplit; ++p)
        s += *(const f32x4*)(part + (size_t)p * (B_ROWS * W_DIM) + i);
    *(f32x4*)(out + i) = s;
}

// ---------------- fallback GEMM (round-1 path, VGPR staging) ---------------
__global__ __launch_bounds__(256, 2) void k_gemm_bt(
    const float* __restrict__ x, const float* __restrict__ dist,
    const unsigned short* __restrict__ Tt, float* __restrict__ part,
    int kchunk)
{
    __shared__ unsigned short As[128][72];
    __shared__ unsigned short Bs[128][64];

    const int bm0 = blockIdx.x * 128;
    const int bn0 = blockIdx.y * 128;
    const int kbase = blockIdx.z * kchunk;

    const int lane = threadIdx.x & 63;
    const int wid  = threadIdx.x >> 6;
    const int wm = wid >> 1, wn = wid & 1;
    const int lq = lane >> 4, lr = lane & 15;

    f32x4 acc[4][4];
#pragma unroll
    for (int a = 0; a < 4; ++a)
#pragma unroll
        for (int b = 0; b < 4; ++b)
            acc[a][b] = (f32x4){0.f, 0.f, 0.f, 0.f};

    const int iters = kchunk / 64;
    for (int it = 0; it < iters; ++it) {
        const int k0 = kbase + it * 64;
        const int l  = k0 >> 9;
        const int i0 = k0 & 511;
#pragma unroll
        for (int r2 = 0; r2 < 8; ++r2) {
            int id = threadIdx.x + r2 * 256;
            int m  = id >> 4;
            int kc = id & 15;
            float sc = dist[(size_t)(bm0 + m) * N_BINS + l];
            f32x4 v = *(const f32x4*)(x + (size_t)(bm0 + m) * D_DIM + i0 + kc * 4);
            v *= sc;
            unsigned int p0 = (unsigned int)f2bf(v.x) | ((unsigned int)f2bf(v.y) << 16);
            unsigned int p1 = (unsigned int)f2bf(v.z) | ((unsigned int)f2bf(v.w) << 16);
            unsigned int* dp = (unsigned int*)&As[m][kc * 4];
            dp[0] = p0; dp[1] = p1;
        }
#pragma unroll
        for (int r2 = 0; r2 < 4; ++r2) {
            int id = threadIdx.x + r2 * 256;
            int n  = id >> 3;
            int cc = id & 7;
            int cg = cc ^ (n & 7);
            const u16x8 v = *(const u16x8*)(Tt + (size_t)(bn0 + n) * K_TOT + k0 + cg * 8);
            *(u16x8*)&Bs[n][cc * 8] = v;
        }
        __syncthreads();
#pragma unroll
        for (int ks = 0; ks < 2; ++ks) {
            bf16x8 af[4], bfr[4];
#pragma unroll
            for (int fm = 0; fm < 4; ++fm)
                af[fm] = *(const bf16x8*)&As[wm * 64 + fm * 16 + lr][ks * 32 + lq * 8];
#pragma unroll
            for (int fn = 0; fn < 4; ++fn) {
                int nl = wn * 64 + fn * 16 + lr;
                int cs = (ks * 4 + lq) ^ (nl & 7);
                bfr[fn] = *(const bf16x8*)&Bs[nl][cs * 8];
            }
#pragma unroll
            for (int fm = 0; fm < 4; ++fm)
#pragma unroll
                for (int fn = 0; fn < 4; ++fn)
                    acc[fm][fn] = __builtin_amdgcn_mfma_f32_16x16x32_bf16(
                        af[fm], bfr[fn], acc[fm][fn], 0, 0, 0);
        }
        __syncthreads();
    }

    float* Cp = part + (size_t)blockIdx.z * (B_ROWS * W_DIM);
#pragma unroll
    for (int fm = 0; fm < 4; ++fm)
#pragma unroll
        for (int fn = 0; fn < 4; ++fn)
#pragma unroll
            for (int r = 0; r < 4; ++r) {
                int row = bm0 + wm * 64 + fm * 16 + lq * 4 + r;
                int col = bn0 + wn * 64 + fn * 16 + lr;
                Cp[(size_t)row * W_DIM + col] = acc[fm][fn][r];
            }
}

extern "C" void kernel_launch(void* const* d_in, const int* in_sizes, int n_in,
                              void* d_out, int out_size, void* d_ws, size_t ws_size,
                              hipStream_t stream) {
    const float* x   = (const float*)d_in[0];
    const float* ray = (const float*)d_in[1];
    const float* w_i = (const float*)d_in[2];
    const float* b_i = (const float*)d_in[3];
    const float* a_i = (const float*)d_in[4];
    const float* T   = (const float*)d_in[5];
    const int*   idx = (const int*)d_in[6];
    float* out = (float*)d_out;

    char* ws = (char*)d_ws;
    const size_t distBytes = (size_t)B_ROWS * N_BINS * 4;        // 512 KiB
    const size_t xbBytes   = (size_t)B_ROWS * D_DIM * 2;         // 2 MiB
    const size_t ttBytes   = (size_t)W_DIM * K_TOT * 2;          // 32 MiB
    const size_t partBytes = (size_t)B_ROWS * W_DIM * 4;         // 4 MiB per split

    if (ws_size >= distBytes + xbBytes + ttBytes + (size_t)NSPLIT * partBytes) {
        // -------- path A: online-rescaled dist-fold GEMM --------
        float*          dist = (float*)ws;
        unsigned short* xb   = (unsigned short*)(ws + distBytes);
        unsigned short* Tt   = (unsigned short*)(ws + distBytes + xbBytes);
        float*          part = (float*)(ws + distBytes + xbBytes + ttBytes);

        k_prep<<<B_ROWS / 4, 256, 0, stream>>>(x, ray, w_i, b_i, a_i, idx, dist, xb);
        k_transpose2<<<dim3(8, 8, 64), 256, 0, stream>>>(T, Tt);
        k_gemm5<<<512, 256, 0, stream>>>(xb, Tt, dist, part);
        k_reduce<<<(B_ROWS * W_DIM) / (256 * 4), 256, 0, stream>>>(part, out, NSPLIT);
    } else if (ws_size >= distBytes + xbBytes + ttBytes) {
        // -------- path B: round-1 structure, nsplit=1 direct to out --------
        float*          dist = (float*)ws;
        unsigned short* xb   = (unsigned short*)(ws + distBytes);
        unsigned short* Tt   = (unsigned short*)(ws + distBytes + xbBytes);
        k_prep<<<B_ROWS / 4, 256, 0, stream>>>(x, ray, w_i, b_i, a_i, idx, dist, xb);
        k_transpose2<<<dim3(8, 8, 64), 256, 0, stream>>>(T, Tt);
        k_gemm_bt<<<dim3(16, 4, 1), 256, 0, stream>>>(x, dist, Tt, out, K_TOT);
    }
}

// Round 6
// 220.629 us; speedup vs baseline: 1.4559x; 1.1280x over previous
//
#include <hip/hip_runtime.h>
#include <math.h>

typedef float  f32x4  __attribute__((ext_vector_type(4)));
typedef short  bf16x8 __attribute__((ext_vector_type(8)));
typedef unsigned short u16x8 __attribute__((ext_vector_type(8)));
typedef unsigned short u16x4 __attribute__((ext_vector_type(4)));

#define B_ROWS 2048
#define D_DIM  512
#define W_DIM  512
#define N_NODES 63
#define N_BINS  64
#define K_TOT   32768   // 64 * 512
#define NSPLIT  16      // 4 l's per z-slot
#define LPS     (N_BINS / NSPLIT)   // l's per split = 4
#define DEPS    1e-12f

__device__ __forceinline__ unsigned short f2bf(float f) {
    union { float f; unsigned int u; } v; v.f = f;
    unsigned int u = v.u;
    return (unsigned short)((u + 0x7fffu + ((u >> 16) & 1u)) >> 16);
}

__device__ __forceinline__ float sigmoidf_(float z) {
    return 1.0f / (1.0f + expf(-z));
}

// async global->LDS, 16 bytes per lane. LDS dest must be wave-uniform base + lane*16.
__device__ __forceinline__ void load_lds16(const void* g, void* l) {
    __builtin_amdgcn_global_load_lds(
        (const __attribute__((address_space(1))) unsigned int*)g,
        (__attribute__((address_space(3))) unsigned int*)l,
        16, 0, 0);
}

// ---------------- kernel 1: fused prep (dist + xb) AND transpose -----------
// blocks [0,4096): transpose T[64][512][512] f32 -> Tt[512][32768] bf16
// blocks [4096,4608): dist [2048,64] + xb = bf16(x)
__global__ __launch_bounds__(256) void k_pre(
    const float* __restrict__ x, const float* __restrict__ ray,
    const float* __restrict__ w_i, const float* __restrict__ b_i,
    const float* __restrict__ a_i, const int* __restrict__ idx,
    const float* __restrict__ T,
    float* __restrict__ dist, unsigned short* __restrict__ xb,
    unsigned short* __restrict__ Tt)
{
    __shared__ float tile[64][65];
    const int bid = blockIdx.x;
    const int t   = threadIdx.x;

    if (bid < 4096) {
        // -------- transpose path --------
        const int i0 = (bid & 7) * 64;
        const int w0 = ((bid >> 3) & 7) * 64;
        const int l  = bid >> 6;

        const int w4 = (t & 15) * 4;
        const int ir = t >> 4;     // 0..15
        const float* src = T + ((size_t)(l * 512 + i0)) * 512 + w0;
#pragma unroll
        for (int p = 0; p < 4; ++p) {
            int i = ir + p * 16;
            f32x4 v = *(const f32x4*)(src + (size_t)i * 512 + w4);
            tile[i][w4 + 0] = v.x; tile[i][w4 + 1] = v.y;
            tile[i][w4 + 2] = v.z; tile[i][w4 + 3] = v.w;
        }
        __syncthreads();
#pragma unroll
        for (int rep = 0; rep < 2; ++rep) {
            int id = t + rep * 256;    // 0..511
            int w  = id >> 3;          // 0..63
            int c  = id & 7;           // i-chunk
            u16x8 o;
#pragma unroll
            for (int j = 0; j < 8; ++j) o[j] = f2bf(tile[c * 8 + j][w]);
            *(u16x8*)(Tt + (size_t)(w0 + w) * K_TOT + l * 512 + i0 + c * 8) = o;
        }
        return;
    }

    // -------- prep path --------
    const int pb   = bid - 4096;          // 0..511
    const int wid  = t >> 6;
    const int lane = t & 63;
    const int row  = pb * 4 + wid;
    const float* xr = x + (size_t)row * D_DIM;

    float dotv = 0.f, xx = 0.f, rr = 0.f;
#pragma unroll
    for (int j = 0; j < 2; ++j) {
        f32x4 xv = *(const f32x4*)(xr  + j * 256 + lane * 4);
        f32x4 rv = *(const f32x4*)(ray + j * 256 + lane * 4);
        dotv += xv.x * rv.x + xv.y * rv.y + xv.z * rv.z + xv.w * rv.w;
        xx   += xv.x * xv.x + xv.y * xv.y + xv.z * xv.z + xv.w * xv.w;
        rr   += rv.x * rv.x + rv.y * rv.y + rv.z * rv.z + rv.w * rv.w;
        u16x4 o;
        o[0] = f2bf(xv.x); o[1] = f2bf(xv.y); o[2] = f2bf(xv.z); o[3] = f2bf(xv.w);
        *(u16x4*)(xb + (size_t)row * D_DIM + j * 256 + lane * 4) = o;
    }
#pragma unroll
    for (int off = 1; off < 64; off <<= 1) {
        dotv += __shfl_xor(dotv, off, 64);
        xx   += __shfl_xor(xx,   off, 64);
        rr   += __shfl_xor(rr,   off, 64);
    }
    float xn = fmaxf(sqrtf(xx), 1e-8f);
    float rn = fmaxf(sqrtf(rr), 1e-8f);
    float cosv = dotv / (xn * rn);
    cosv = fminf(1.f, fmaxf(-1.f, cosv));
    float angle = acosf(cosv) * 0.31830988618379067f; // 1/pi

    float dec = 0.f;
    if (lane < N_NODES) {
        float sw = sigmoidf_(w_i[lane]);
        float sb = sigmoidf_(b_i[lane]);
        float nf = (0.5f + sw) * angle - sb;
        dec = sigmoidf_(nf * (1.0f + a_i[lane]));
    }

    float p = 1.f;
#pragma unroll
    for (int v = 0; v < 6; ++v) {
        int j = idx[lane * 6 + v];
        int node = (j < N_NODES) ? j : j - N_NODES;
        float d = __shfl(dec, node, 64);
        p *= (j < N_NODES) ? d : (1.0f - d);
    }
    dist[(size_t)row * N_BINS + lane] = p;
}

// ---------------- kernel 2: online-rescaled dist-fold GEMM, 4 blocks/CU ----
// Single accumulator; acc kept in units of current segment's dist dc[l]:
// boundary acc *= dc[l-1]/dc[l]; epilogue * dc[last]. Grid 1024 linear,
// XCD-combo swizzle. NSPLIT=16 -> 4 l-segments (K=2048) per block.
__global__ __launch_bounds__(256, 4) void k_gemm6(
    const unsigned short* __restrict__ xb, const unsigned short* __restrict__ Tt,
    const float* __restrict__ dist, float* __restrict__ part)
{
    __shared__ unsigned short As[128 * 64];
    __shared__ unsigned short Bs[128 * 64];
    __shared__ float Ds[128 * LPS];

    const int b   = blockIdx.x;
    const int xcd = b & 7;
    const int j   = b >> 3;               // 0..127
    const int combo = xcd * 8 + (j >> 4); // 0..63
    const int mblk  = j & 15;
    const int bm0 = mblk * 128;
    const int bn0 = (combo & 3) * 128;
    const int z   = combo >> 2;           // 0..15
    const int l0  = z * LPS;

    const int t    = threadIdx.x;
    const int lane = t & 63;
    const int wid  = t >> 6;
    const int wm = wid >> 1, wn = wid & 1;
    const int lq = lane >> 4, lr = lane & 15;

    const int srow = t >> 3;   // 0..31 (+ j*32)
    const int c    = t & 7;    // LDS chunk slot

    // preload dist tile [128 rows][LPS l's] -> LDS
    if (t < 128) {
        f32x4 dv = *(const f32x4*)(dist + (size_t)(bm0 + t) * N_BINS + l0);
        *(f32x4*)&Ds[t * LPS] = dv;
    }
    __syncthreads();

    f32x4 acc[4][4];
#pragma unroll
    for (int a = 0; a < 4; ++a)
#pragma unroll
        for (int bb = 0; bb < 4; ++bb)
            acc[a][bb] = (f32x4){0.f, 0.f, 0.f, 0.f};

    for (int lo = 0; lo < LPS; ++lo) {
        const int l = l0 + lo;

        // segment-boundary rescale: acc *= dc[lo-1]/dc[lo]
        if (lo > 0) {
#pragma unroll
            for (int fm = 0; fm < 4; ++fm)
#pragma unroll
                for (int r = 0; r < 4; ++r) {
                    int m = wm * 64 + fm * 16 + lq * 4 + r;
                    float dp = fmaxf(Ds[m * LPS + lo - 1], DEPS);
                    float dn = fmaxf(Ds[m * LPS + lo],     DEPS);
                    float ratio = dp * __builtin_amdgcn_rcpf(dn);
#pragma unroll
                    for (int fn = 0; fn < 4; ++fn)
                        acc[fm][fn][r] *= ratio;
                }
        }

        for (int it = 0; it < 8; ++it) {
            const int i0 = it * 64;
#pragma unroll
            for (int jj = 0; jj < 4; ++jj) {
                int row = srow + jj * 32;
                int cg  = c ^ (row & 7);
                load_lds16(xb + (size_t)(bm0 + row) * D_DIM + i0 + cg * 8,
                           &As[row * 64 + c * 8]);
                load_lds16(Tt + (size_t)(bn0 + row) * K_TOT + l * 512 + i0 + cg * 8,
                           &Bs[row * 64 + c * 8]);
            }
            __syncthreads();
#pragma unroll
            for (int ks = 0; ks < 2; ++ks) {
                bf16x8 af[4], bfr[4];
#pragma unroll
                for (int fm = 0; fm < 4; ++fm) {
                    int m = wm * 64 + fm * 16 + lr;
                    int g = ks * 4 + lq;
                    af[fm] = *(const bf16x8*)&As[m * 64 + ((g ^ (m & 7)) * 8)];
                }
#pragma unroll
                for (int fn = 0; fn < 4; ++fn) {
                    int n = wn * 64 + fn * 16 + lr;
                    int g = ks * 4 + lq;
                    bfr[fn] = *(const bf16x8*)&Bs[n * 64 + ((g ^ (n & 7)) * 8)];
                }
#pragma unroll
                for (int fm = 0; fm < 4; ++fm)
#pragma unroll
                    for (int fn = 0; fn < 4; ++fn)
                        acc[fm][fn] = __builtin_amdgcn_mfma_f32_16x16x32_bf16(
                            af[fm], bfr[fn], acc[fm][fn], 0, 0, 0);
            }
            __syncthreads();
        }
    }

    // epilogue: multiply by dc[last] and store partial
    float* Cp = part + (size_t)z * (B_ROWS * W_DIM);
#pragma unroll
    for (int fm = 0; fm < 4; ++fm)
#pragma unroll
        for (int r = 0; r < 4; ++r) {
            int m = wm * 64 + fm * 16 + lq * 4 + r;
            float dl = fmaxf(Ds[m * LPS + LPS - 1], DEPS);
#pragma unroll
            for (int fn = 0; fn < 4; ++fn) {
                int col = bn0 + wn * 64 + fn * 16 + lr;
                Cp[(size_t)(bm0 + m) * W_DIM + col] = acc[fm][fn][r] * dl;
            }
        }
}

// ---------------- kernel 3: split reduction --------------------------------
__global__ __launch_bounds__(256) void k_reduce(
    const float* __restrict__ part, float* __restrict__ out, int nsplit)
{
    int i = (blockIdx.x * 256 + threadIdx.x) * 4;
    f32x4 s = *(const f32x4*)(part + i);
    for (int p = 1; p < nsplit; ++p)
        s += *(const f32x4*)(part + (size_t)p * (B_ROWS * W_DIM) + i);
    *(f32x4*)(out + i) = s;
}

// ---------------- fallback GEMM (round-1 path, VGPR staging) ---------------
__global__ __launch_bounds__(256, 2) void k_gemm_bt(
    const float* __restrict__ x, const float* __restrict__ dist,
    const unsigned short* __restrict__ Tt, float* __restrict__ part,
    int kchunk)
{
    __shared__ unsigned short As[128][72];
    __shared__ unsigned short Bs[128][64];

    const int bm0 = blockIdx.x * 128;
    const int bn0 = blockIdx.y * 128;
    const int kbase = blockIdx.z * kchunk;

    const int lane = threadIdx.x & 63;
    const int wid  = threadIdx.x >> 6;
    const int wm = wid >> 1, wn = wid & 1;
    const int lq = lane >> 4, lr = lane & 15;

    f32x4 acc[4][4];
#pragma unroll
    for (int a = 0; a < 4; ++a)
#pragma unroll
        for (int b = 0; b < 4; ++b)
            acc[a][b] = (f32x4){0.f, 0.f, 0.f, 0.f};

    const int iters = kchunk / 64;
    for (int it = 0; it < iters; ++it) {
        const int k0 = kbase + it * 64;
        const int l  = k0 >> 9;
        const int i0 = k0 & 511;
#pragma unroll
        for (int r2 = 0; r2 < 8; ++r2) {
            int id = threadIdx.x + r2 * 256;
            int m  = id >> 4;
            int kc = id & 15;
            float sc = dist[(size_t)(bm0 + m) * N_BINS + l];
            f32x4 v = *(const f32x4*)(x + (size_t)(bm0 + m) * D_DIM + i0 + kc * 4);
            v *= sc;
            unsigned int p0 = (unsigned int)f2bf(v.x) | ((unsigned int)f2bf(v.y) << 16);
            unsigned int p1 = (unsigned int)f2bf(v.z) | ((unsigned int)f2bf(v.w) << 16);
            unsigned int* dp = (unsigned int*)&As[m][kc * 4];
            dp[0] = p0; dp[1] = p1;
        }
#pragma unroll
        for (int r2 = 0; r2 < 4; ++r2) {
            int id = threadIdx.x + r2 * 256;
            int n  = id >> 3;
            int cc = id & 7;
            int cg = cc ^ (n & 7);
            const u16x8 v = *(const u16x8*)(Tt + (size_t)(bn0 + n) * K_TOT + k0 + cg * 8);
            *(u16x8*)&Bs[n][cc * 8] = v;
        }
        __syncthreads();
#pragma unroll
        for (int ks = 0; ks < 2; ++ks) {
            bf16x8 af[4], bfr[4];
#pragma unroll
            for (int fm = 0; fm < 4; ++fm)
                af[fm] = *(const bf16x8*)&As[wm * 64 + fm * 16 + lr][ks * 32 + lq * 8];
#pragma unroll
            for (int fn = 0; fn < 4; ++fn) {
                int nl = wn * 64 + fn * 16 + lr;
                int cs = (ks * 4 + lq) ^ (nl & 7);
                bfr[fn] = *(const bf16x8*)&Bs[nl][cs * 8];
            }
#pragma unroll
            for (int fm = 0; fm < 4; ++fm)
#pragma unroll
                for (int fn = 0; fn < 4; ++fn)
                    acc[fm][fn] = __builtin_amdgcn_mfma_f32_16x16x32_bf16(
                        af[fm], bfr[fn], acc[fm][fn], 0, 0, 0);
        }
        __syncthreads();
    }

    float* Cp = part + (size_t)blockIdx.z * (B_ROWS * W_DIM);
#pragma unroll
    for (int fm = 0; fm < 4; ++fm)
#pragma unroll
        for (int fn = 0; fn < 4; ++fn)
#pragma unroll
            for (int r = 0; r < 4; ++r) {
                int row = bm0 + wm * 64 + fm * 16 + lq * 4 + r;
                int col = bn0 + wn * 64 + fn * 16 + lr;
                Cp[(size_t)row * W_DIM + col] = acc[fm][fn][r];
            }
}

extern "C" void kernel_launch(void* const* d_in, const int* in_sizes, int n_in,
                              void* d_out, int out_size, void* d_ws, size_t ws_size,
                              hipStream_t stream) {
    const float* x   = (const float*)d_in[0];
    const float* ray = (const float*)d_in[1];
    const float* w_i = (const float*)d_in[2];
    const float* b_i = (const float*)d_in[3];
    const float* a_i = (const float*)d_in[4];
    const float* T   = (const float*)d_in[5];
    const int*   idx = (const int*)d_in[6];
    float* out = (float*)d_out;

    char* ws = (char*)d_ws;
    const size_t distBytes = (size_t)B_ROWS * N_BINS * 4;        // 512 KiB
    const size_t xbBytes   = (size_t)B_ROWS * D_DIM * 2;         // 2 MiB
    const size_t ttBytes   = (size_t)W_DIM * K_TOT * 2;          // 32 MiB
    const size_t partBytes = (size_t)B_ROWS * W_DIM * 4;         // 4 MiB per split

    float*          dist = (float*)ws;
    unsigned short* xb   = (unsigned short*)(ws + distBytes);
    unsigned short* Tt   = (unsigned short*)(ws + distBytes + xbBytes);

    if (ws_size >= distBytes + xbBytes + ttBytes + (size_t)NSPLIT * partBytes) {
        // -------- path A: 4-blocks/CU online-rescaled dist-fold GEMM --------
        float* part = (float*)(ws + distBytes + xbBytes + ttBytes);

        k_pre<<<4096 + 512, 256, 0, stream>>>(x, ray, w_i, b_i, a_i, idx, T,
                                              dist, xb, Tt);
        k_gemm6<<<1024, 256, 0, stream>>>(xb, Tt, dist, part);
        k_reduce<<<(B_ROWS * W_DIM) / (256 * 4), 256, 0, stream>>>(part, out, NSPLIT);
    } else if (ws_size >= distBytes + xbBytes + ttBytes) {
        // -------- path B: round-1 structure, nsplit=1 direct to out --------
        k_pre<<<4096 + 512, 256, 0, stream>>>(x, ray, w_i, b_i, a_i, idx, T,
                                              dist, xb, Tt);
        k_gemm_bt<<<dim3(16, 4, 1), 256, 0, stream>>>(x, dist, Tt, out, K_TOT);
    }
}